// Round 15
// baseline (27.056 us; speedup 1.0000x reference)
//
#include <hip/hip_runtime.h>

#define FDIM 32
#define LOG2E 1.44269504088896340f

typedef _Float16 half8  __attribute__((ext_vector_type(8)));
typedef float    f32x4  __attribute__((ext_vector_type(4)));
typedef float    f32x16 __attribute__((ext_vector_type(16)));

// base-2 sigmoid: z' = z*log2e pre-scaled; sigma = 1/(1+2^-z')
__device__ __forceinline__ float fsig2(float z2) {
    return __builtin_amdgcn_rcpf(1.0f + __builtin_amdgcn_exp2f(-z2));
}
// true sigmoid (prep only)
__device__ __forceinline__ float fsig(float z) {
    return __builtin_amdgcn_rcpf(1.0f + __builtin_amdgcn_exp2f(-z * LOG2E));
}

// 32x32 MFMA C-layout: col = lane&31 (sample), row32 = (r&3)+8*(r>>2)+4*hb,
// hb = lane>>5, r = C-reg 0..15. Global A-row rho = 32*b + row32 (block b of 8).
// Row permutation: lane (sample, hb), block b, reg r  ->  tree slot so that each
// lane's 16 regs = one complete depth-4 subtree J = 8*hb+b (15 nodes) + 1 path node.
//   r 0..7   -> L7: slot 128+8J+r   (leaf pair t=r)
//   r 8..11  -> L6: slot 64+4J+(r-8)
//   r 12..13 -> L5: slot 32+2J+(r-12)
//   r 14     -> L4: slot 16+J
//   r 15     -> path node: hb=0: {1,2,4,5,8,9,10,11}[b]; hb=1: {1,3,6,7,12,13,14,15}[b]
__device__ __forceinline__ int slot_of(int b, int hb, int r) {
    int J = 8 * hb + b;
    if (r < 8)   return 128 + 8 * J + r;
    if (r < 12)  return 64 + 4 * J + (r - 8);
    if (r < 14)  return 32 + 2 * J + (r - 12);
    if (r == 14) return 16 + J;
    if (b == 0)  return 1;                    // root (duplicated for both hb)
    if (b == 1)  return 2 + hb;
    if (b < 4)   return 4 + 2 * hb + (b - 2);
    return 8 + 4 * hb + (b - 4);
}

// Prep (4 blocks x 256 thr; 4 threads per row, 8 k's each):
// Wh[rho][32] = relu(fi[slot-1])*log2e f16 (permuted), negc[b*32+hb*16+r] =
// -c*log2e, Dtab[16J+2t] = {cls0-cls1, cls1} for leaf pair t of subtree J.
__global__ void dtree_prep(const float* __restrict__ fi, const float* __restrict__ fs,
                           const float* __restrict__ cls,
                           _Float16* __restrict__ Wh, float* __restrict__ negc,
                           float* __restrict__ Dtab) {
    int t = blockIdx.x * 256 + threadIdx.x;   // 0..1023
    if (t < 128) {
        float c0 = cls[2 * t], c1 = cls[2 * t + 1];
        Dtab[2 * t]     = c0 - c1;
        Dtab[2 * t + 1] = c1;
    }
    int rho = t >> 2, q = t & 3;              // permuted row, k-quad
    int b = rho >> 5, row32 = rho & 31;
    int hb = (row32 >> 2) & 1;
    int r = (row32 & 3) + 4 * (row32 >> 3);
    int node = slot_of(b, hb, r) - 1;
    half8 wv;
    float s = 0.0f;
#pragma unroll
    for (int k0 = 0; k0 < 8; ++k0) {
        int k = 8 * q + k0;
        float w = fi[(node << 5) + k];
        w = w > 0.0f ? w : 0.0f;
        wv[k0] = (_Float16)(w * LOG2E);
        s = fmaf(w, fsig(fs[(node << 5) + k]), s);
    }
    *(half8*)(Wh + (rho << 5) + 8 * q) = wv;
    s += __shfl_xor(s, 1, 64);
    s += __shfl_xor(s, 2, 64);
    if (q == 0) negc[b * 32 + hb * 16 + r] = -s * LOG2E;
}

// Fused: 2 fully-independent waves/block (wave-private LDS, no barrier),
// 32 samples/wave. 2-deep accumulator software pipeline: MFMA pair for block
// b+1 issues before block b's sigmoid/combine consumes its accumulator.
__global__ __launch_bounds__(128, 5) void dtree_fused(
    const float* __restrict__ x, const _Float16* __restrict__ Wh,
    const float* __restrict__ negc, const float* __restrict__ Dtab,
    float* __restrict__ out)
{
    __shared__ __align__(64) float sNegc[2][256];   // per-wave copies
    __shared__ __align__(64) float sDtab[2][256];

    const int tid = threadIdx.x;
    const int w = tid >> 6;          // wave in block (0/1)
    const int l = tid & 63;
    const int s32 = l & 31;          // sample col
    const int hb = l >> 5;           // half-wave group
    const int n = blockIdx.x * 64 + w * 32 + s32;

    // Wave-private staging (issued first so it's in flight early).
    ((f32x4*)sNegc[w])[l] = ((const f32x4*)negc)[l];
    ((f32x4*)sDtab[w])[l] = ((const f32x4*)Dtab)[l];

    // B fragments: frag0 = x[n][8hb..8hb+7] (k 0..15), frag1 = x[n][16+8hb..]
    const float* xrow = x + (size_t)n * FDIM;
    f32x4 xa = *(const f32x4*)(xrow + 8 * hb);
    f32x4 xb = *(const f32x4*)(xrow + 8 * hb + 4);
    f32x4 xc = *(const f32x4*)(xrow + 16 + 8 * hb);
    f32x4 xd = *(const f32x4*)(xrow + 16 + 8 * hb + 4);
    half8 bf0, bf1;
    bf0[0] = (_Float16)xa[0]; bf0[1] = (_Float16)xa[1];
    bf0[2] = (_Float16)xa[2]; bf0[3] = (_Float16)xa[3];
    bf0[4] = (_Float16)xb[0]; bf0[5] = (_Float16)xb[1];
    bf0[6] = (_Float16)xb[2]; bf0[7] = (_Float16)xb[3];
    bf1[0] = (_Float16)xc[0]; bf1[1] = (_Float16)xc[1];
    bf1[2] = (_Float16)xc[2]; bf1[3] = (_Float16)xc[3];
    bf1[4] = (_Float16)xd[0]; bf1[5] = (_Float16)xd[1];
    bf1[6] = (_Float16)xd[2]; bf1[7] = (_Float16)xd[3];

    // Wave-local producer->consumer through LDS: wave-local wait only.
    asm volatile("s_waitcnt lgkmcnt(0)" ::: "memory");
    __builtin_amdgcn_sched_barrier(0);

    const float* nw = sNegc[w];
    const float* dw = sDtab[w];

#define APTR(b) (Wh + ((32 * (b) + s32) << 5) + 8 * hb)

    // MFMA pair for block b into accumulator ACC (C-init = -c from LDS).
#define MF(b, A0, A1, ACC) do { \
    f32x16 ci_ = *(const f32x16*)(nw + (b) * 32 + hb * 16); \
    ACC = __builtin_amdgcn_mfma_f32_32x32x16_f16(A0, bf0, ci_, 0, 0, 0); \
    ACC = __builtin_amdgcn_mfma_f32_32x32x16_f16(A1, bf1, ACC, 0, 0, 0); \
} while (0)

    // Consume accumulator: 16 sigmoids + upward combine of subtree J=8hb+b.
#define CONS(b, AC, vout, pgout) do { \
    const float* dj_ = dw + (8 * hb + (b)) * 16; \
    f32x4 dA_ = *(const f32x4*)(dj_); \
    f32x4 dB_ = *(const f32x4*)(dj_ + 4); \
    f32x4 dC_ = *(const f32x4*)(dj_ + 8); \
    f32x4 dD_ = *(const f32x4*)(dj_ + 12); \
    float v70_ = fmaf(fsig2(AC[0]), dA_[0], dA_[1]); \
    float v71_ = fmaf(fsig2(AC[1]), dA_[2], dA_[3]); \
    float v72_ = fmaf(fsig2(AC[2]), dB_[0], dB_[1]); \
    float v73_ = fmaf(fsig2(AC[3]), dB_[2], dB_[3]); \
    float v74_ = fmaf(fsig2(AC[4]), dC_[0], dC_[1]); \
    float v75_ = fmaf(fsig2(AC[5]), dC_[2], dC_[3]); \
    float v76_ = fmaf(fsig2(AC[6]), dD_[0], dD_[1]); \
    float v77_ = fmaf(fsig2(AC[7]), dD_[2], dD_[3]); \
    float v60_ = fmaf(fsig2(AC[8]),  v70_ - v71_, v71_); \
    float v61_ = fmaf(fsig2(AC[9]),  v72_ - v73_, v73_); \
    float v62_ = fmaf(fsig2(AC[10]), v74_ - v75_, v75_); \
    float v63_ = fmaf(fsig2(AC[11]), v76_ - v77_, v77_); \
    float v50_ = fmaf(fsig2(AC[12]), v60_ - v61_, v61_); \
    float v51_ = fmaf(fsig2(AC[13]), v62_ - v63_, v63_); \
    vout = fmaf(fsig2(AC[14]), v50_ - v51_, v51_); \
    pgout = fsig2(AC[15]); \
} while (0)

    float v0, v1, v2, v3, v4, v5, v6, v7;
    float pg0, pg1, pg2, pg3, pg4, pg5, pg6, pg7;
    f32x16 accA, accB;

    // 2-deep pipeline: load b+1 ahead, MFMA b+1 before consuming b.
    half8 p0a = *(const half8*)APTR(0);
    half8 p0b = *(const half8*)(APTR(0) + 16);
    half8 p1a = *(const half8*)APTR(1);
    half8 p1b = *(const half8*)(APTR(1) + 16);
    MF(0, p0a, p0b, accA);
    half8 p2a = *(const half8*)APTR(2);
    half8 p2b = *(const half8*)(APTR(2) + 16);
    MF(1, p1a, p1b, accB);
    CONS(0, accA, v0, pg0);
    half8 p3a = *(const half8*)APTR(3);
    half8 p3b = *(const half8*)(APTR(3) + 16);
    MF(2, p2a, p2b, accA);
    CONS(1, accB, v1, pg1);
    half8 p4a = *(const half8*)APTR(4);
    half8 p4b = *(const half8*)(APTR(4) + 16);
    MF(3, p3a, p3b, accB);
    CONS(2, accA, v2, pg2);
    half8 p5a = *(const half8*)APTR(5);
    half8 p5b = *(const half8*)(APTR(5) + 16);
    MF(4, p4a, p4b, accA);
    CONS(3, accB, v3, pg3);
    half8 p6a = *(const half8*)APTR(6);
    half8 p6b = *(const half8*)(APTR(6) + 16);
    MF(5, p5a, p5b, accB);
    CONS(4, accA, v4, pg4);
    half8 p7a = *(const half8*)APTR(7);
    half8 p7b = *(const half8*)(APTR(7) + 16);
    MF(6, p6a, p6b, accA);
    CONS(5, accB, v5, pg5);
    MF(7, p7a, p7b, accB);
    CONS(6, accA, v6, pg6);
    CONS(7, accB, v7, pg7);
#undef MF
#undef CONS
#undef APTR

    // Path prefix products. pg0=root, pg1=slot 2+hb, pg2/3=slots 4/5+2hb,
    // pg4..7=slots 8..11+4hb. Subtree jj=b: bits (jj>>2, jj>>1&1, jj&1).
    float f0   = hb ? (1.0f - pg0) : pg0;
    float a01  = f0 * pg1;
    float a01n = f0 - a01;                    // f0*(1-pg1)
    float t0 = a01  * pg2, t1 = a01  - t0;
    float t2 = a01n * pg3, t3 = a01n - t2;
    float p0 = t0 * pg4, p1 = t0 - p0;
    float p2 = t1 * pg5, p3 = t1 - p2;
    float p4 = t2 * pg6, p5 = t2 - p4;
    float p6 = t3 * pg7, p7 = t3 - p6;

    float facc = p0 * v0;
    facc = fmaf(p1, v1, facc);
    facc = fmaf(p2, v2, facc);
    facc = fmaf(p3, v3, facc);
    facc = fmaf(p4, v4, facc);
    facc = fmaf(p5, v5, facc);
    facc = fmaf(p6, v6, facc);
    facc = fmaf(p7, v7, facc);

    // combine the two hb-halves of each sample
    facc += __shfl_xor(facc, 32, 64);
    if (l < 32) out[n] = facc;
}

extern "C" void kernel_launch(void* const* d_in, const int* in_sizes, int n_in,
                              void* d_out, int out_size, void* d_ws, size_t ws_size,
                              hipStream_t stream) {
    const float* x   = (const float*)d_in[0];
    const float* fi  = (const float*)d_in[1];
    const float* fs  = (const float*)d_in[2];
    const float* cls = (const float*)d_in[3];

    _Float16* Wh = (_Float16*)d_ws;                        // 256*32*2 = 16 KB
    float* negc  = (float*)((char*)d_ws + 16384);          // 1 KB
    float* Dtab  = negc + 256;                             // 1 KB

    int nsamp = in_sizes[0] / FDIM;                        // 262144
    float* out = (float*)d_out;

    hipLaunchKernelGGL(dtree_prep, dim3(4), dim3(256), 0, stream, fi, fs, cls, Wh, negc, Dtab);
    hipLaunchKernelGGL(dtree_fused, dim3(nsamp / 64), dim3(128), 0, stream,
                       x, Wh, negc, Dtab, out);
}

// Round 16
// 26.408 us; speedup vs baseline: 1.0245x; 1.0245x over previous
//
#include <hip/hip_runtime.h>

#define FDIM 32
#define LOG2E 1.44269504088896340f

typedef _Float16 half8  __attribute__((ext_vector_type(8)));
typedef float    f32x4  __attribute__((ext_vector_type(4)));
typedef float    f32x16 __attribute__((ext_vector_type(16)));

// base-2 sigmoid: z' = z*log2e pre-scaled; sigma = 1/(1+2^-z')
__device__ __forceinline__ float fsig2(float z2) {
    return __builtin_amdgcn_rcpf(1.0f + __builtin_amdgcn_exp2f(-z2));
}
// true sigmoid (prep only)
__device__ __forceinline__ float fsig(float z) {
    return __builtin_amdgcn_rcpf(1.0f + __builtin_amdgcn_exp2f(-z * LOG2E));
}

// 32x32 MFMA C-layout: col = lane&31 (sample), row32 = (r&3)+8*(r>>2)+4*hb,
// hb = lane>>5, r = C-reg 0..15. Global A-row rho = 32*b + row32 (block b of 8).
// Row permutation: lane (sample, hb), block b, reg r  ->  tree slot so that each
// lane's 16 regs = one complete depth-4 subtree J = 8*hb+b (15 nodes) + 1 path node.
//   r 0..7   -> L7: slot 128+8J+r   (leaf pair t=r)
//   r 8..11  -> L6: slot 64+4J+(r-8)
//   r 12..13 -> L5: slot 32+2J+(r-12)
//   r 14     -> L4: slot 16+J
//   r 15     -> path node: hb=0: {1,2,4,5,8,9,10,11}[b]; hb=1: {1,3,6,7,12,13,14,15}[b]
__device__ __forceinline__ int slot_of(int b, int hb, int r) {
    int J = 8 * hb + b;
    if (r < 8)   return 128 + 8 * J + r;
    if (r < 12)  return 64 + 4 * J + (r - 8);
    if (r < 14)  return 32 + 2 * J + (r - 12);
    if (r == 14) return 16 + J;
    if (b == 0)  return 1;                    // root (duplicated for both hb)
    if (b == 1)  return 2 + hb;
    if (b < 4)   return 4 + 2 * hb + (b - 2);
    return 8 + 4 * hb + (b - 4);
}

// Prep (4 blocks x 256 thr; 4 threads per row, 8 k's each):
// Wh[rho][32] = relu(fi[slot-1])*log2e f16 (permuted), negc[b*32+hb*16+r] =
// -c*log2e, Dtab[16J+2t] = {cls0-cls1, cls1} for leaf pair t of subtree J.
__global__ void dtree_prep(const float* __restrict__ fi, const float* __restrict__ fs,
                           const float* __restrict__ cls,
                           _Float16* __restrict__ Wh, float* __restrict__ negc,
                           float* __restrict__ Dtab) {
    int t = blockIdx.x * 256 + threadIdx.x;   // 0..1023
    if (t < 128) {
        float c0 = cls[2 * t], c1 = cls[2 * t + 1];
        Dtab[2 * t]     = c0 - c1;
        Dtab[2 * t + 1] = c1;
    }
    int rho = t >> 2, q = t & 3;              // permuted row, k-quad
    int b = rho >> 5, row32 = rho & 31;
    int hb = (row32 >> 2) & 1;
    int r = (row32 & 3) + 4 * (row32 >> 3);
    int node = slot_of(b, hb, r) - 1;
    half8 wv;
    float s = 0.0f;
#pragma unroll
    for (int k0 = 0; k0 < 8; ++k0) {
        int k = 8 * q + k0;
        float w = fi[(node << 5) + k];
        w = w > 0.0f ? w : 0.0f;
        wv[k0] = (_Float16)(w * LOG2E);
        s = fmaf(w, fsig(fs[(node << 5) + k]), s);
    }
    *(half8*)(Wh + (rho << 5) + 8 * q) = wv;
    s += __shfl_xor(s, 1, 64);
    s += __shfl_xor(s, 2, 64);
    if (q == 0) negc[b * 32 + hb * 16 + r] = -s * LOG2E;
}

// Fused: 2 fully-independent waves/block (wave-private LDS, no barrier),
// 32 samples/wave. 1-deep prefetch of BOTH the A fragments (VMEM) and the
// C-init cin (LDS->reg, rotating ciA/ciB) so no MFMA waits on a just-issued
// load. Dtab reads stay in CONS (hidden behind 16 independent sigmoids).
__global__ __launch_bounds__(128, 5) void dtree_fused(
    const float* __restrict__ x, const _Float16* __restrict__ Wh,
    const float* __restrict__ negc, const float* __restrict__ Dtab,
    float* __restrict__ out)
{
    __shared__ __align__(64) float sNegc[2][256];   // per-wave copies
    __shared__ __align__(64) float sDtab[2][256];

    const int tid = threadIdx.x;
    const int w = tid >> 6;          // wave in block (0/1)
    const int l = tid & 63;
    const int s32 = l & 31;          // sample col
    const int hb = l >> 5;           // half-wave group
    const int n = blockIdx.x * 64 + w * 32 + s32;

    // Wave-private staging (issued first so it's in flight early).
    ((f32x4*)sNegc[w])[l] = ((const f32x4*)negc)[l];
    ((f32x4*)sDtab[w])[l] = ((const f32x4*)Dtab)[l];

    // B fragments: frag0 = x[n][8hb..8hb+7] (k 0..15), frag1 = x[n][16+8hb..]
    const float* xrow = x + (size_t)n * FDIM;
    f32x4 xa = *(const f32x4*)(xrow + 8 * hb);
    f32x4 xb = *(const f32x4*)(xrow + 8 * hb + 4);
    f32x4 xc = *(const f32x4*)(xrow + 16 + 8 * hb);
    f32x4 xd = *(const f32x4*)(xrow + 16 + 8 * hb + 4);
    half8 bf0, bf1;
    bf0[0] = (_Float16)xa[0]; bf0[1] = (_Float16)xa[1];
    bf0[2] = (_Float16)xa[2]; bf0[3] = (_Float16)xa[3];
    bf0[4] = (_Float16)xb[0]; bf0[5] = (_Float16)xb[1];
    bf0[6] = (_Float16)xb[2]; bf0[7] = (_Float16)xb[3];
    bf1[0] = (_Float16)xc[0]; bf1[1] = (_Float16)xc[1];
    bf1[2] = (_Float16)xc[2]; bf1[3] = (_Float16)xc[3];
    bf1[4] = (_Float16)xd[0]; bf1[5] = (_Float16)xd[1];
    bf1[6] = (_Float16)xd[2]; bf1[7] = (_Float16)xd[3];

    // Wave-local producer->consumer through LDS: wave-local wait only.
    asm volatile("s_waitcnt lgkmcnt(0)" ::: "memory");
    __builtin_amdgcn_sched_barrier(0);

    const float* nw = sNegc[w];
    const float* dw = sDtab[w];

#define APTR(b) (Wh + ((32 * (b) + s32) << 5) + 8 * hb)
#define CIPTR(b) ((const f32x16*)(nw + (b) * 32 + hb * 16))

    // MFMA pair for block b from pre-loaded A fragments and pre-read cin.
#define MF(A0, A1, CI, ACC) do { \
    ACC = __builtin_amdgcn_mfma_f32_32x32x16_f16(A0, bf0, CI, 0, 0, 0); \
    ACC = __builtin_amdgcn_mfma_f32_32x32x16_f16(A1, bf1, ACC, 0, 0, 0); \
} while (0)

    // Consume accumulator: 16 sigmoids + upward combine of subtree J=8hb+b.
#define CONS(b, AC, vout, pgout) do { \
    const float* dj_ = dw + (8 * hb + (b)) * 16; \
    f32x4 dA_ = *(const f32x4*)(dj_); \
    f32x4 dB_ = *(const f32x4*)(dj_ + 4); \
    f32x4 dC_ = *(const f32x4*)(dj_ + 8); \
    f32x4 dD_ = *(const f32x4*)(dj_ + 12); \
    float v70_ = fmaf(fsig2(AC[0]), dA_[0], dA_[1]); \
    float v71_ = fmaf(fsig2(AC[1]), dA_[2], dA_[3]); \
    float v72_ = fmaf(fsig2(AC[2]), dB_[0], dB_[1]); \
    float v73_ = fmaf(fsig2(AC[3]), dB_[2], dB_[3]); \
    float v74_ = fmaf(fsig2(AC[4]), dC_[0], dC_[1]); \
    float v75_ = fmaf(fsig2(AC[5]), dC_[2], dC_[3]); \
    float v76_ = fmaf(fsig2(AC[6]), dD_[0], dD_[1]); \
    float v77_ = fmaf(fsig2(AC[7]), dD_[2], dD_[3]); \
    float v60_ = fmaf(fsig2(AC[8]),  v70_ - v71_, v71_); \
    float v61_ = fmaf(fsig2(AC[9]),  v72_ - v73_, v73_); \
    float v62_ = fmaf(fsig2(AC[10]), v74_ - v75_, v75_); \
    float v63_ = fmaf(fsig2(AC[11]), v76_ - v77_, v77_); \
    float v50_ = fmaf(fsig2(AC[12]), v60_ - v61_, v61_); \
    float v51_ = fmaf(fsig2(AC[13]), v62_ - v63_, v63_); \
    vout = fmaf(fsig2(AC[14]), v50_ - v51_, v51_); \
    pgout = fsig2(AC[15]); \
} while (0)

    float v0, v1, v2, v3, v4, v5, v6, v7;
    float pg0, pg1, pg2, pg3, pg4, pg5, pg6, pg7;
    f32x16 acc;

    // Pipeline: A(b+1) VMEM loads + ci(b+1) LDS read issue before CONS(b).
    half8 c0_0 = *(const half8*)APTR(0);
    half8 c1_0 = *(const half8*)(APTR(0) + 16);
    f32x16 ciA = *CIPTR(0);
    half8 c0_1 = *(const half8*)APTR(1);
    half8 c1_1 = *(const half8*)(APTR(1) + 16);
    f32x16 ciB = *CIPTR(1);
    MF(c0_0, c1_0, ciA, acc);

    half8 c0_2 = *(const half8*)APTR(2);
    half8 c1_2 = *(const half8*)(APTR(2) + 16);
    ciA = *CIPTR(2);
    CONS(0, acc, v0, pg0);
    MF(c0_1, c1_1, ciB, acc);

    half8 c0_3 = *(const half8*)APTR(3);
    half8 c1_3 = *(const half8*)(APTR(3) + 16);
    ciB = *CIPTR(3);
    CONS(1, acc, v1, pg1);
    MF(c0_2, c1_2, ciA, acc);

    half8 c0_4 = *(const half8*)APTR(4);
    half8 c1_4 = *(const half8*)(APTR(4) + 16);
    ciA = *CIPTR(4);
    CONS(2, acc, v2, pg2);
    MF(c0_3, c1_3, ciB, acc);

    half8 c0_5 = *(const half8*)APTR(5);
    half8 c1_5 = *(const half8*)(APTR(5) + 16);
    ciB = *CIPTR(5);
    CONS(3, acc, v3, pg3);
    MF(c0_4, c1_4, ciA, acc);

    half8 c0_6 = *(const half8*)APTR(6);
    half8 c1_6 = *(const half8*)(APTR(6) + 16);
    ciA = *CIPTR(6);
    CONS(4, acc, v4, pg4);
    MF(c0_5, c1_5, ciB, acc);

    half8 c0_7 = *(const half8*)APTR(7);
    half8 c1_7 = *(const half8*)(APTR(7) + 16);
    ciB = *CIPTR(7);
    CONS(5, acc, v5, pg5);
    MF(c0_6, c1_6, ciA, acc);

    CONS(6, acc, v6, pg6);
    MF(c0_7, c1_7, ciB, acc);
    CONS(7, acc, v7, pg7);
#undef MF
#undef CONS
#undef APTR
#undef CIPTR

    // Path prefix products. pg0=root, pg1=slot 2+hb, pg2/3=slots 4/5+2hb,
    // pg4..7=slots 8..11+4hb. Subtree jj=b: bits (jj>>2, jj>>1&1, jj&1).
    float f0   = hb ? (1.0f - pg0) : pg0;
    float a01  = f0 * pg1;
    float a01n = f0 - a01;                    // f0*(1-pg1)
    float t0 = a01  * pg2, t1 = a01  - t0;
    float t2 = a01n * pg3, t3 = a01n - t2;
    float p0 = t0 * pg4, p1 = t0 - p0;
    float p2 = t1 * pg5, p3 = t1 - p2;
    float p4 = t2 * pg6, p5 = t2 - p4;
    float p6 = t3 * pg7, p7 = t3 - p6;

    float facc = p0 * v0;
    facc = fmaf(p1, v1, facc);
    facc = fmaf(p2, v2, facc);
    facc = fmaf(p3, v3, facc);
    facc = fmaf(p4, v4, facc);
    facc = fmaf(p5, v5, facc);
    facc = fmaf(p6, v6, facc);
    facc = fmaf(p7, v7, facc);

    // combine the two hb-halves of each sample
    facc += __shfl_xor(facc, 32, 64);
    if (l < 32) out[n] = facc;
}

extern "C" void kernel_launch(void* const* d_in, const int* in_sizes, int n_in,
                              void* d_out, int out_size, void* d_ws, size_t ws_size,
                              hipStream_t stream) {
    const float* x   = (const float*)d_in[0];
    const float* fi  = (const float*)d_in[1];
    const float* fs  = (const float*)d_in[2];
    const float* cls = (const float*)d_in[3];

    _Float16* Wh = (_Float16*)d_ws;                        // 256*32*2 = 16 KB
    float* negc  = (float*)((char*)d_ws + 16384);          // 1 KB
    float* Dtab  = negc + 256;                             // 1 KB

    int nsamp = in_sizes[0] / FDIM;                        // 262144
    float* out = (float*)d_out;

    hipLaunchKernelGGL(dtree_prep, dim3(4), dim3(256), 0, stream, fi, fs, cls, Wh, negc, Dtab);
    hipLaunchKernelGGL(dtree_fused, dim3(nsamp / 64), dim3(128), 0, stream,
                       x, Wh, negc, Dtab, out);
}